// Round 3
// baseline (748.068 us; speedup 1.0000x reference)
//
#include <hip/hip_runtime.h>
#include <math.h>

// Decoder_9887014716020 — fp32, R2: register-staged DCN gather (T14 split).
// B=2, H=W=64 (HW=4096), HD=40, N_NODES=6, 10 edges.

#define HWSH 12      // 4096 = 1<<12

__device__ __constant__ int c_src[10] = {0,1,1,1,2,2,3,4,4,5};
__device__ __constant__ int c_dst[10] = {1,0,2,4,1,3,2,1,5,4};

// ---- workspace layout (float offsets) ----
constexpr size_t NODES_OFF = 0;                         // 2*240*4096
constexpr size_t BG_OFF    = 1966080;                   // 2*40*4096
constexpr size_t H1_OFF    = 2293760;                   // 10*2*80*4096
constexpr size_t OM_OFF    = 8847360;                   // 10*2*27*4096
constexpr size_t MSGS_OFF  = 11059200;                  // 6*2*40*4096
constexpr size_t NEWBN_OFF = 13025280;                  // 2*240*4096
constexpr size_t WT1_OFF   = 14991360;                  // 10*9*80*80
constexpr size_t WT2_OFF   = 15567488;                  // 10*9*80*40
constexpr size_t WO1T_OFF  = 15855616;                  // 10*80*9*27
constexpr size_t WO2T_OFF  = 16050144;                  // 10*80*9*27
constexpr size_t PWT_OFF   = 16244672;                  // 256*240
constexpr size_t BGWT_OFF  = 16306240;                  // 768*40
constexpr size_t UW1T_OFF  = 16337088;                  // 6*80*32
constexpr size_t UW2T_OFF  = 16352576;                  // 6*32*40

__device__ inline float relu_(float x){ return x > 0.f ? x : 0.f; }
__device__ inline float sigm_(float x){ return 1.f/(1.f + __expf(-x)); }

// ---- weight transposes into ws ----
__global__ __launch_bounds__(256) void k_tr(
    const float* __restrict__ dcn1w, const float* __restrict__ dcn2w,
    const float* __restrict__ off1w, const float* __restrict__ off2w,
    const float* __restrict__ p_w,  const float* __restrict__ bg_w,
    const float* __restrict__ u_w1, const float* __restrict__ u_w2,
    float* __restrict__ ws)
{
  int idx = blockIdx.x*256 + threadIdx.x;
  if (idx < 576000){                               // wt1[e][k][c][o]
    int o = idx%80; int t = idx/80; int c = t%80; t/=80; int k = t%9; int e = t/9;
    ws[WT1_OFF+idx] = dcn1w[(size_t)((e*80+o)*80+c)*9+k];
  } else if (idx < 864000){                        // wt2[e][k][c][o]
    int i = idx-576000;
    int o=i%40; int t=i/40; int c=t%80; t/=80; int k=t%9; int e=t/9;
    ws[WT2_OFF+i] = dcn2w[(size_t)((e*40+o)*80+c)*9+k];
  } else if (idx < 1058400){                       // wo1t[e][c][ktap][oc]
    int i = idx-864000;
    int oc=i%27; int t=i/27; int kk=t%9; t/=9; int c=t%80; int e=t/80;
    ws[WO1T_OFF+i] = off1w[(size_t)((e*27+oc)*80+c)*9+kk];
  } else if (idx < 1252800){                       // wo2t
    int i = idx-1058400;
    int oc=i%27; int t=i/27; int kk=t%9; t/=9; int c=t%80; int e=t/80;
    ws[WO2T_OFF+i] = off2w[(size_t)((e*27+oc)*80+c)*9+kk];
  } else if (idx < 1314240){                       // pwt[c][o]
    int i = idx-1252800;
    int o=i%240; int c=i/240;
    ws[PWT_OFF+i] = p_w[(size_t)o*256+c];
  } else if (idx < 1344960){                       // bgwt[c][o]
    int i = idx-1314240;
    int o=i%40; int c=i/40;
    ws[BGWT_OFF+i] = bg_w[(size_t)o*768+c];
  } else if (idx < 1360320){                       // uw1t[n][c][o]
    int i = idx-1344960;
    int o=i%32; int t=i/32; int c=t%80; int n=t/80;
    ws[UW1T_OFF+i] = u_w1[(size_t)((n*32+o)*80)+c];
  } else if (idx < 1368000){                       // uw2t[n][c][o]
    int i = idx-1360320;
    int o=i%40; int t=i/40; int c=t%32; int n=t/32;
    ws[UW2T_OFF+i] = u_w2[(size_t)((n*40+o)*32)+c];
  }
}

__global__ __launch_bounds__(256) void k_zero(float* __restrict__ p, int n){
  int i = blockIdx.x*256+threadIdx.x;
  if (i < n) p[i] = 0.f;
}

// ---- nodes = bnr(xp @ p_w^T) : [2,240,4096] ----
__global__ __launch_bounds__(256) void k_nodes(
    const float* __restrict__ xp, const float* __restrict__ pwt,
    const float* __restrict__ g, const float* __restrict__ bb,
    float* __restrict__ nodes)
{
  const int row = blockIdx.x;
  const int b = row >> 6;
  const int off = ((row & 63) << 6) + (threadIdx.x & 63);
  const int wv = __builtin_amdgcn_readfirstlane(threadIdx.x >> 6);
  const int o0 = blockIdx.y*40 + wv*10;
  float acc[10];
  #pragma unroll
  for (int j=0;j<10;j++) acc[j]=0.f;
  const float* xb = xp + (((size_t)b)<<20) + off;
  #pragma unroll 2
  for (int c=0;c<256;c++){
    float xv = xb[((size_t)c)<<HWSH];
    const float* wr = pwt + c*240 + o0;
    #pragma unroll
    for (int j=0;j<10;j++) acc[j] = fmaf(xv, wr[j], acc[j]);
  }
  #pragma unroll
  for (int j=0;j<10;j++){
    int o = o0+j;
    nodes[(((size_t)(b*240+o))<<HWSH)+off] = relu_(g[o]*acc[j]+bb[o]);
  }
}

// ---- bg = bnr(concat(xp,xh,xf) @ bg_w^T) : [2,40,4096] ----
__global__ __launch_bounds__(256) void k_bg(
    const float* __restrict__ xp, const float* __restrict__ xh, const float* __restrict__ xf,
    const float* __restrict__ bgwt, const float* __restrict__ g, const float* __restrict__ bb,
    float* __restrict__ bg)
{
  const int row = blockIdx.x;
  const int b = row >> 6;
  const int off = ((row & 63) << 6) + (threadIdx.x & 63);
  const int wv = __builtin_amdgcn_readfirstlane(threadIdx.x >> 6);
  const int o0 = blockIdx.y*20 + wv*5;
  float acc[5];
  #pragma unroll
  for (int j=0;j<5;j++) acc[j]=0.f;
  const float* srcs[3] = {xp, xh, xf};
  #pragma unroll
  for (int part=0;part<3;part++){
    const float* xb = srcs[part] + (((size_t)b)<<20) + off;
    const float* wp = bgwt + part*256*40 + o0;
    #pragma unroll 2
    for (int c=0;c<256;c++){
      float xv = xb[((size_t)c)<<HWSH];
      const float* wr = wp + c*40;
      #pragma unroll
      for (int j=0;j<5;j++) acc[j] = fmaf(xv, wr[j], acc[j]);
    }
  }
  #pragma unroll
  for (int j=0;j<5;j++){
    int o = o0+j;
    bg[(((size_t)(b*40+o))<<HWSH)+off] = relu_(g[o]*acc[j]+bb[o]);
  }
}

// ---- offsets conv 3x3 SAME: 80ch -> 27ch, per edge ----
template<int STAGE>
__global__ __launch_bounds__(256) void k_off(
    const float* __restrict__ nodes, const float* __restrict__ h1,
    const float* __restrict__ wot, const float* __restrict__ bo,
    float* __restrict__ om)
{
  const int bid = blockIdx.x;
  const int e = bid >> 7;
  const int b = (bid >> 6) & 1;
  const int h = bid & 63;
  const int p = threadIdx.x & 63;
  const int wv = __builtin_amdgcn_readfirstlane(threadIdx.x >> 6);
  const int o0 = wv*7;
  const int no = (wv==3) ? 6 : 7;
  const int sn = c_src[e], dn = c_dst[e];
  float acc[7];
  #pragma unroll
  for (int j=0;j<7;j++) acc[j] = (j<no) ? bo[e*27+o0+j] : 0.f;
  #pragma unroll 2
  for (int c=0;c<80;c++){
    const float* cb;
    if (STAGE==1){
      int cc = (c<40) ? (sn*40+c) : (dn*40+c-40);
      cb = nodes + (((size_t)(b*240+cc))<<HWSH);
    } else {
      cb = h1 + (((size_t)((e*2+b)*80+c))<<HWSH);
    }
    const float* wc = wot + (size_t)((e*80+c)*9)*27 + o0;
    #pragma unroll
    for (int ky=0;ky<3;ky++){
      int hy = h+ky-1;
      if (hy < 0 || hy > 63) continue;
      float x0 = cb[(hy<<6) + p];
      float xm = __shfl_up(x0, 1);
      float xq = __shfl_down(x0, 1);
      xm = (p>0)  ? xm : 0.f;
      xq = (p<63) ? xq : 0.f;
      const float* wr = wc + ky*81;     // [ktap=ky*3+kx][oc], 27 per tap
      #pragma unroll
      for (int j=0;j<7;j++){
        acc[j] = fmaf(xm, wr[j],    acc[j]);
        acc[j] = fmaf(x0, wr[27+j], acc[j]);
        acc[j] = fmaf(xq, wr[54+j], acc[j]);
      }
    }
  }
  const int off = (h<<6)+p;
  for (int j=0;j<no;j++)
    om[(((size_t)((e*2+b)*27 + o0 + j))<<HWSH)+off] = acc[j];
}

// ---- DCN sample + conv + bnr (+stage2: attention + atomic msg accum) ----
// grid 1280 = e*128 + b*64 + h; block 256 = 64 px * 4 waves.
// Register-staged half-tap pipeline: per iteration
//   {issue 40 corner loads(t+1) -> rv[]} || {compute(t) from LDS} -> blend+write(t+1) -> barrier.
// om values preloaded to registers so address math has no memory dependency.
template<int STAGE>
__global__ __launch_bounds__(256) void k_dcn(
    const float* __restrict__ nodes, const float* __restrict__ h1,
    const float* __restrict__ om, const float* __restrict__ wt,
    const float* __restrict__ bng, const float* __restrict__ bnb,
    const float* __restrict__ attw, const float* __restrict__ attb,
    float* __restrict__ outp)
{
  constexpr int OUTC = (STAGE==1) ? 80 : 40;
  constexpr int PER  = OUTC/4;
  __shared__ float s_lds[2][40][64];    // 20 KB
  const int bid = blockIdx.x;
  const int e = bid >> 7;
  const int b = (bid >> 6) & 1;
  const int h = bid & 63;
  const int p = threadIdx.x & 63;
  const int wv = __builtin_amdgcn_readfirstlane(threadIdx.x >> 6);
  const int off = (h<<6) + p;
  const int sn = c_src[e], dn = c_dst[e];

  // preload all 27 offset-map values for this pixel into registers
  const float* ombase = om + (((size_t)((e*2+b)*27))<<HWSH) + off;
  float omv[27];
  #pragma unroll
  for (int i=0;i<27;i++) omv[i] = ombase[((size_t)i)<<HWSH];

  // wave-uniform gather bases for the two channel-halves
  const float* base0;
  const float* base1;
  if (STAGE==1){
    base0 = nodes + (((size_t)(b*240 + sn*40 + wv*10))<<HWSH);
    base1 = nodes + (((size_t)(b*240 + dn*40 + wv*10))<<HWSH);
  } else {
    base0 = h1 + (((size_t)((e*2+b)*80 + wv*10))<<HWSH);
    base1 = h1 + (((size_t)((e*2+b)*80 + 40 + wv*10))<<HWSH);
  }

  float acc[PER];
  #pragma unroll
  for (int j=0;j<PER;j++) acc[j]=0.f;

  float w00,w01,w10,w11; int a00,a01,a10,a11;
  #define MKCTX(kk) do { \
    const int k_ = (kk); \
    float dyv = omv[2*k_], dxv = omv[2*k_+1]; \
    float mv  = sigm_(omv[18+k_]); \
    float py = dyv + (float)(k_/3 - 1 + h); \
    float px = dxv + (float)(k_%3 - 1 + p); \
    float y0f = floorf(py), x0f = floorf(px); \
    float wy = py - y0f, wx = px - x0f; \
    int y0 = (int)y0f, x0i = (int)x0f; \
    int y1 = y0+1, x1i = x0i+1; \
    bool yv0 = (y0>=0)&&(y0<64),  yv1 = (y1>=0)&&(y1<64); \
    bool xv0 = (x0i>=0)&&(x0i<64), xv1 = (x1i>=0)&&(x1i<64); \
    w00 = (yv0&&xv0) ? (1.f-wy)*(1.f-wx)*mv : 0.f; \
    w01 = (yv0&&xv1) ? (1.f-wy)*wx*mv       : 0.f; \
    w10 = (yv1&&xv0) ? wy*(1.f-wx)*mv       : 0.f; \
    w11 = (yv1&&xv1) ? wy*wx*mv             : 0.f; \
    int yc0 = min(max(y0 ,0),63), yc1 = min(max(y1 ,0),63); \
    int xc0 = min(max(x0i,0),63), xc1 = min(max(x1i,0),63); \
    a00 = (yc0<<6)+xc0; a01 = (yc0<<6)+xc1; \
    a10 = (yc1<<6)+xc0; a11 = (yc1<<6)+xc1; \
  } while(0)

  float rv[40];

  // prologue: gather+write tap-half 0
  MKCTX(0);
  #pragma unroll
  for (int j=0;j<10;j++){
    const float* cb = base0 + (((size_t)j)<<HWSH);
    rv[4*j+0]=cb[a00]; rv[4*j+1]=cb[a01]; rv[4*j+2]=cb[a10]; rv[4*j+3]=cb[a11];
  }
  #pragma unroll
  for (int j=0;j<10;j++){
    float sv = fmaf(w00,rv[4*j+0], fmaf(w01,rv[4*j+1], fmaf(w10,rv[4*j+2], w11*rv[4*j+3])));
    s_lds[0][wv*10+j][p] = sv;
  }
  __syncthreads();

  for (int t=0; t<17; t++){
    const int tn = t+1;
    // 1) issue corner loads for t+1 (register destinations, no wait yet)
    MKCTX(tn>>1);
    const float* bb_ = (tn&1) ? base1 : base0;
    #pragma unroll
    for (int j=0;j<10;j++){
      const float* cb = bb_ + (((size_t)j)<<HWSH);
      rv[4*j+0]=cb[a00]; rv[4*j+1]=cb[a01]; rv[4*j+2]=cb[a10]; rv[4*j+3]=cb[a11];
    }
    // 2) compute tap-half t from LDS (hides the load latency)
    {
      const int k = t >> 1, half = t & 1;
      const float* wk = wt + (size_t)((e*9+k)*80 + half*40)*OUTC + wv*PER;
      #pragma unroll 4
      for (int c=0;c<40;c++){
        float sv = s_lds[t&1][c][p];
        const float* wr = wk + c*OUTC;
        #pragma unroll
        for (int j=0;j<PER;j++) acc[j] = fmaf(sv, wr[j], acc[j]);
      }
    }
    // 3) blend + LDS write for t+1 (first use of the loads -> single wait here)
    #pragma unroll
    for (int j=0;j<10;j++){
      float sv = fmaf(w00,rv[4*j+0], fmaf(w01,rv[4*j+1], fmaf(w10,rv[4*j+2], w11*rv[4*j+3])));
      s_lds[tn&1][wv*10+j][p] = sv;
    }
    __syncthreads();
  }
  // epilogue: compute t=17 (k=8, half=1, buf 1)
  {
    const float* wk = wt + (size_t)((e*9+8)*80 + 40)*OUTC + wv*PER;
    #pragma unroll 4
    for (int c=0;c<40;c++){
      float sv = s_lds[1][c][p];
      const float* wr = wk + c*OUTC;
      #pragma unroll
      for (int j=0;j<PER;j++) acc[j] = fmaf(sv, wr[j], acc[j]);
    }
  }
  #undef MKCTX

  if (STAGE==1){
    #pragma unroll
    for (int j=0;j<PER;j++){
      int o = wv*PER+j;
      outp[(((size_t)((e*2+b)*80+o))<<HWSH)+off] = relu_(bng[e*80+o]*acc[j] + bnb[e*80+o]);
    }
  } else {
    float at = attb[e];
    for (int c=0;c<40;c++)
      at = fmaf(nodes[(((size_t)(b*240+sn*40+c))<<HWSH)+off], attw[e*40+c], at);
    float fac = 2.f - sigm_(at);
    #pragma unroll
    for (int j=0;j<PER;j++){
      int o = wv*PER+j;
      float v = relu_(bng[e*40+o]*acc[j] + bnb[e*40+o]);
      atomicAdd(&outp[(((size_t)((dn*2+b)*40+o))<<HWSH)+off], v*fac);
    }
  }
}

// ---- node update: 2-layer 1x1 MLP -> new_bn [2,240,4096] ----
__global__ __launch_bounds__(128) void k_upd(
    const float* __restrict__ nodes, const float* __restrict__ msgs,
    const float* __restrict__ uw1t, const float* __restrict__ g1, const float* __restrict__ b1,
    const float* __restrict__ uw2t, const float* __restrict__ g2, const float* __restrict__ b2,
    float* __restrict__ newbn)
{
  const int bid = blockIdx.x;
  const int n = bid >> 6;
  const int r = bid & 63;
  const int b = r >> 5;
  const int pix = ((r & 31) << 7) + threadIdx.x;
  float a1[32];
  #pragma unroll
  for (int j=0;j<32;j++) a1[j]=0.f;
  for (int c=0;c<40;c++){
    float xv = nodes[(((size_t)(b*240+n*40+c))<<HWSH)+pix];
    const float* wr = uw1t + (n*80+c)*32;
    #pragma unroll
    for (int j=0;j<32;j++) a1[j]=fmaf(xv,wr[j],a1[j]);
  }
  for (int c=0;c<40;c++){
    float xv = msgs[(((size_t)((n*2+b)*40+c))<<HWSH)+pix];
    const float* wr = uw1t + (n*80+40+c)*32;
    #pragma unroll
    for (int j=0;j<32;j++) a1[j]=fmaf(xv,wr[j],a1[j]);
  }
  #pragma unroll
  for (int j=0;j<32;j++) a1[j] = relu_(g1[n*32+j]*a1[j]+b1[n*32+j]);
  float a2[40];
  #pragma unroll
  for (int j=0;j<40;j++) a2[j]=0.f;
  for (int c=0;c<32;c++){
    const float* wr = uw2t + (n*32+c)*40;
    #pragma unroll
    for (int j=0;j<40;j++) a2[j]=fmaf(a1[c],wr[j],a2[j]);
  }
  #pragma unroll
  for (int j=0;j<40;j++)
    newbn[(((size_t)(b*240+n*40+j))<<HWSH)+pix] = relu_(g2[n*40+j]*a2[j]+b2[n*40+j]);
}

// ---- xp_infer concat (float4) ----
__global__ __launch_bounds__(256) void k_out(
    const float* __restrict__ xp, const float* __restrict__ bg,
    const float* __restrict__ newbn, float* __restrict__ out)
{
  int i4 = blockIdx.x*256+threadIdx.x;   // 1097728 float4 groups
  if (i4 >= 1097728) return;
  int idx = i4 << 2;
  int b = idx / (536*4096);
  int r = idx - b*(536*4096);
  int ch = r >> HWSH;
  int off = r & 4095;
  float4 v;
  if (ch < 256)      v = *(const float4*)&xp[(((size_t)(b*256+ch))<<HWSH)+off];
  else if (ch < 296) v = *(const float4*)&bg[(((size_t)(b*40+ch-256))<<HWSH)+off];
  else               v = *(const float4*)&newbn[(((size_t)(b*240+ch-296))<<HWSH)+off];
  *(float4*)&out[idx] = v;
}

// ---- pg classifier ----
__global__ __launch_bounds__(256) void k_pg(
    const float* __restrict__ nodes, const float* __restrict__ newbn,
    const float* __restrict__ bg,
    const float* __restrict__ cw, const float* __restrict__ cb,
    const float* __restrict__ cnw, const float* __restrict__ cnb,
    float* __restrict__ out)
{
  int idx = blockIdx.x*256+threadIdx.x;   // exactly 57344 threads
  int b = idx / (7*4096);
  int r = idx - b*7*4096;
  int g = r >> HWSH;
  int off = r & 4095;
  float a = cb[g] + cnb[g];
  if (g == 0){
    for (int c=0;c<40;c++){
      float v = bg[(((size_t)(b*40+c))<<HWSH)+off];
      a = fmaf(v, cw[c]+cnw[c], a);
    }
  } else {
    for (int c=0;c<40;c++){
      float vo = nodes[(((size_t)(b*240+(g-1)*40+c))<<HWSH)+off];
      float vn = newbn[(((size_t)(b*240+(g-1)*40+c))<<HWSH)+off];
      a = fmaf(vo, cw[g*40+c], a);
      a = fmaf(vn, cnw[g*40+c], a);
    }
  }
  out[4390912 + idx] = a;
}

extern "C" void kernel_launch(void* const* d_in, const int* in_sizes, int n_in,
                              void* d_out, int out_size, void* d_ws, size_t ws_size,
                              hipStream_t stream)
{
  const float* xp       = (const float*)d_in[0];
  const float* xh       = (const float*)d_in[1];
  const float* xf       = (const float*)d_in[2];
  const float* p_w      = (const float*)d_in[3];
  const float* p_g      = (const float*)d_in[4];
  const float* p_b      = (const float*)d_in[5];
  const float* bg_w     = (const float*)d_in[6];
  const float* bg_g     = (const float*)d_in[7];
  const float* bg_b     = (const float*)d_in[8];
  const float* e_off1_w = (const float*)d_in[9];
  const float* e_off1_b = (const float*)d_in[10];
  const float* e_dcn1_w = (const float*)d_in[11];
  const float* e_bn1_g  = (const float*)d_in[12];
  const float* e_bn1_b  = (const float*)d_in[13];
  const float* e_off2_w = (const float*)d_in[14];
  const float* e_off2_b = (const float*)d_in[15];
  const float* e_dcn2_w = (const float*)d_in[16];
  const float* e_bn2_g  = (const float*)d_in[17];
  const float* e_bn2_b  = (const float*)d_in[18];
  const float* e_att_w  = (const float*)d_in[19];
  const float* e_att_b  = (const float*)d_in[20];
  const float* u_w1     = (const float*)d_in[21];
  const float* u_g1     = (const float*)d_in[22];
  const float* u_b1     = (const float*)d_in[23];
  const float* u_w2     = (const float*)d_in[24];
  const float* u_g2     = (const float*)d_in[25];
  const float* u_b2     = (const float*)d_in[26];
  const float* cls_w    = (const float*)d_in[27];
  const float* cls_b    = (const float*)d_in[28];
  const float* cls_nw   = (const float*)d_in[29];
  const float* cls_nb   = (const float*)d_in[30];

  float* ws    = (float*)d_ws;
  float* nodes = ws + NODES_OFF;
  float* bgb   = ws + BG_OFF;
  float* h1    = ws + H1_OFF;
  float* om    = ws + OM_OFF;
  float* msgs  = ws + MSGS_OFF;
  float* newbn = ws + NEWBN_OFF;
  float* wt1   = ws + WT1_OFF;
  float* wt2   = ws + WT2_OFF;
  float* wo1t  = ws + WO1T_OFF;
  float* wo2t  = ws + WO2T_OFF;
  float* pwt   = ws + PWT_OFF;
  float* bgwt  = ws + BGWT_OFF;
  float* uw1t  = ws + UW1T_OFF;
  float* uw2t  = ws + UW2T_OFF;

  k_tr<<<5344, 256, 0, stream>>>(e_dcn1_w, e_dcn2_w, e_off1_w, e_off2_w,
                                 p_w, bg_w, u_w1, u_w2, ws);
  k_zero<<<7680, 256, 0, stream>>>(msgs, 1966080);
  k_nodes<<<dim3(128,6), 256, 0, stream>>>(xp, pwt, p_g, p_b, nodes);
  k_bg<<<dim3(128,2), 256, 0, stream>>>(xp, xh, xf, bgwt, bg_g, bg_b, bgb);
  k_off<1><<<1280, 256, 0, stream>>>(nodes, nullptr, wo1t, e_off1_b, om);
  k_dcn<1><<<1280, 256, 0, stream>>>(nodes, nullptr, om, wt1, e_bn1_g, e_bn1_b,
                                     nullptr, nullptr, h1);
  k_off<2><<<1280, 256, 0, stream>>>(nullptr, h1, wo2t, e_off2_b, om);
  k_dcn<2><<<1280, 256, 0, stream>>>(nodes, h1, om, wt2, e_bn2_g, e_bn2_b,
                                     e_att_w, e_att_b, msgs);
  k_upd<<<384, 128, 0, stream>>>(nodes, msgs, uw1t, u_g1, u_b1, uw2t, u_g2, u_b2, newbn);
  k_out<<<4288, 256, 0, stream>>>(xp, bgb, newbn, (float*)d_out);
  k_pg<<<224, 256, 0, stream>>>(nodes, newbn, bgb, cls_w, cls_b, cls_nw, cls_nb,
                                (float*)d_out);
}

// Round 4
// 673.585 us; speedup vs baseline: 1.1106x; 1.1106x over previous
//
#include <hip/hip_runtime.h>
#include <math.h>

// Decoder_9887014716020 — R3: MFMA (bf16 hi/lo emulation) for DCN conv.
// B=2, H=W=64 (HW=4096), HD=40, N_NODES=6, 10 edges.

#define HWSH 12      // 4096 = 1<<12

__device__ __constant__ int c_src[10] = {0,1,1,1,2,2,3,4,4,5};
__device__ __constant__ int c_dst[10] = {1,0,2,4,1,3,2,1,5,4};

typedef __attribute__((ext_vector_type(8))) short short8;
typedef __attribute__((ext_vector_type(4))) float f32x4;

// ---- workspace layout (float offsets) ----
constexpr size_t NODES_OFF = 0;                         // 2*240*4096
constexpr size_t BG_OFF    = 1966080;                   // 2*40*4096
constexpr size_t H1_OFF    = 2293760;                   // 10*2*80*4096
constexpr size_t OM_OFF    = 8847360;                   // 10*2*27*4096
constexpr size_t MSGS_OFF  = 11059200;                  // 6*2*40*4096
constexpr size_t NEWBN_OFF = 13025280;                  // 2*240*4096
constexpr size_t BS1_OFF   = 14991360;                  // bf16 B-frags stage1: 691200 ushort
constexpr size_t BS2_OFF   = 15336960;                  // stage2: 414720 ushort
constexpr size_t WO1T_OFF  = 15855616;                  // 10*80*9*27
constexpr size_t WO2T_OFF  = 16050144;
constexpr size_t PWT_OFF   = 16244672;                  // 256*240
constexpr size_t BGWT_OFF  = 16306240;                  // 768*40
constexpr size_t UW1T_OFF  = 16337088;                  // 6*80*32
constexpr size_t UW2T_OFF  = 16352576;                  // 6*32*40

__device__ inline float relu_(float x){ return x > 0.f ? x : 0.f; }
__device__ inline float sigm_(float x){ return 1.f/(1.f + __expf(-x)); }
__device__ inline unsigned short bf16rne(float x){
  unsigned int u = __float_as_uint(x);
  unsigned int r = (u + 0x7fffu + ((u>>16)&1u)) >> 16;
  return (unsigned short)r;
}
__device__ inline float bf16f(unsigned short h){
  return __uint_as_float(((unsigned int)h)<<16);
}

// ======== k_pre: zero msgs + weight transposes + bf16 B-fragment prepack ====
// grid partitions: [0,7680) zero | [7680,9649) transposes | [9649,9987) bs1 | [9987,10190) bs2
__global__ __launch_bounds__(256) void k_pre(
    const float* __restrict__ off1w, const float* __restrict__ off2w,
    const float* __restrict__ p_w,  const float* __restrict__ bg_w,
    const float* __restrict__ u_w1, const float* __restrict__ u_w2,
    const float* __restrict__ dcn1w, const float* __restrict__ dcn2w,
    float* __restrict__ ws)
{
  const int bid = blockIdx.x;
  const int tid = threadIdx.x;
  if (bid < 7680){
    ws[MSGS_OFF + bid*256 + tid] = 0.f;                       // zero msgs
  } else if (bid < 9649){
    int i = (bid-7680)*256 + tid;
    if (i < 194400){                       // wo1t[e][c][ktap][oc]
      int oc=i%27; int t=i/27; int kk=t%9; t/=9; int c=t%80; int e=t/80;
      ws[WO1T_OFF+i] = off1w[(size_t)((e*27+oc)*80+c)*9+kk];
    } else if (i < 388800){
      int j = i-194400;
      int oc=j%27; int t=j/27; int kk=t%9; t/=9; int c=t%80; int e=t/80;
      ws[WO2T_OFF+j] = off2w[(size_t)((e*27+oc)*80+c)*9+kk];
    } else if (i < 450240){                // pwt[c][o]
      int j = i-388800;
      int o=j%240; int c=j/240;
      ws[PWT_OFF+j] = p_w[(size_t)o*256+c];
    } else if (i < 480960){                // bgwt[c][o]
      int j = i-450240;
      int o=j%40; int c=j/40;
      ws[BGWT_OFF+j] = bg_w[(size_t)o*768+c];
    } else if (i < 496320){                // uw1t[n][c][o]
      int j = i-480960;
      int o=j%32; int t=j/32; int c=t%80; int n=t/80;
      ws[UW1T_OFF+j] = u_w1[(size_t)((n*32+o)*80)+c];
    } else if (i < 504000){                // uw2t[n][c][o]
      int j = i-496320;
      int o=j%40; int t=j/40; int c=t%32; int n=t/32;
      ws[UW2T_OFF+j] = u_w2[(size_t)((n*40+o)*32)+c];
    }
  } else if (bid < 9987){
    // bs1: B fragments stage1. q = ((e*9+k)*3+kst)*5+nt, per lane 8 bf16.
    int t = (bid-9649)*256 + tid;
    if (t < 86400){
      int lane = t & 63; int q = t >> 6;
      int nt = q % 5; int q2 = q/5; int kst = q2 % 3; q2/=3; int k = q2 % 9; int e = q2/9;
      int n  = nt*16 + (lane & 15);
      int c0 = kst*32 + (lane>>4)*8;
      union { unsigned int u[4]; } r;
      unsigned short v[8];
      #pragma unroll
      for (int j=0;j<8;j++){
        int c = c0 + j;
        float w = (c < 80) ? dcn1w[(size_t)((e*80+n)*80+c)*9+k] : 0.f;
        v[j] = bf16rne(w);
      }
      #pragma unroll
      for (int j=0;j<4;j++) r.u[j] = (unsigned int)v[2*j] | ((unsigned int)v[2*j+1]<<16);
      unsigned int* dst = (unsigned int*)((unsigned short*)(ws + BS1_OFF) + (size_t)t*8);
      dst[0]=r.u[0]; dst[1]=r.u[1]; dst[2]=r.u[2]; dst[3]=r.u[3];
    }
  } else if (bid < 10190){
    // bs2: q = ((e*9+k)*3+kst)*3+nt
    int t = (bid-9987)*256 + tid;
    if (t < 51840){
      int lane = t & 63; int q = t >> 6;
      int nt = q % 3; int q2 = q/3; int kst = q2 % 3; q2/=3; int k = q2 % 9; int e = q2/9;
      int n  = nt*16 + (lane & 15);
      int c0 = kst*32 + (lane>>4)*8;
      union { unsigned int u[4]; } r;
      unsigned short v[8];
      #pragma unroll
      for (int j=0;j<8;j++){
        int c = c0 + j;
        float w = (n < 40 && c < 80) ? dcn2w[(size_t)((e*40+n)*80+c)*9+k] : 0.f;
        v[j] = bf16rne(w);
      }
      #pragma unroll
      for (int j=0;j<4;j++) r.u[j] = (unsigned int)v[2*j] | ((unsigned int)v[2*j+1]<<16);
      unsigned int* dst = (unsigned int*)((unsigned short*)(ws + BS2_OFF) + (size_t)t*8);
      dst[0]=r.u[0]; dst[1]=r.u[1]; dst[2]=r.u[2]; dst[3]=r.u[3];
    }
  }
}

// ======== k_gemm1: nodes (768 blocks) + bg (256 blocks) fused =========
__global__ __launch_bounds__(256) void k_gemm1(
    const float* __restrict__ xp, const float* __restrict__ xh, const float* __restrict__ xf,
    const float* __restrict__ pwt, const float* __restrict__ pg, const float* __restrict__ pb,
    const float* __restrict__ bgwt, const float* __restrict__ gg, const float* __restrict__ gb,
    float* __restrict__ nodes, float* __restrict__ bg)
{
  const int wv = __builtin_amdgcn_readfirstlane(threadIdx.x >> 6);
  if (blockIdx.x < 768){
    const int row = blockIdx.x & 127;
    const int yg  = blockIdx.x >> 7;        // 0..5
    const int b = row >> 6;
    const int off = ((row & 63) << 6) + (threadIdx.x & 63);
    const int o0 = yg*40 + wv*10;
    float acc[10];
    #pragma unroll
    for (int j=0;j<10;j++) acc[j]=0.f;
    const float* xb = xp + (((size_t)b)<<20) + off;
    #pragma unroll 2
    for (int c=0;c<256;c++){
      float xv = xb[((size_t)c)<<HWSH];
      const float* wr = pwt + c*240 + o0;
      #pragma unroll
      for (int j=0;j<10;j++) acc[j] = fmaf(xv, wr[j], acc[j]);
    }
    #pragma unroll
    for (int j=0;j<10;j++){
      int o = o0+j;
      nodes[(((size_t)(b*240+o))<<HWSH)+off] = relu_(pg[o]*acc[j]+pb[o]);
    }
  } else {
    const int r2 = blockIdx.x - 768;
    const int row = r2 & 127;
    const int yg  = r2 >> 7;                // 0..1
    const int b = row >> 6;
    const int off = ((row & 63) << 6) + (threadIdx.x & 63);
    const int o0 = yg*20 + wv*5;
    float acc[5];
    #pragma unroll
    for (int j=0;j<5;j++) acc[j]=0.f;
    const float* srcs[3] = {xp, xh, xf};
    #pragma unroll
    for (int part=0;part<3;part++){
      const float* xb = srcs[part] + (((size_t)b)<<20) + off;
      const float* wp = bgwt + part*256*40 + o0;
      #pragma unroll 2
      for (int c=0;c<256;c++){
        float xv = xb[((size_t)c)<<HWSH];
        const float* wr = wp + c*40;
        #pragma unroll
        for (int j=0;j<5;j++) acc[j] = fmaf(xv, wr[j], acc[j]);
      }
    }
    #pragma unroll
    for (int j=0;j<5;j++){
      int o = o0+j;
      bg[(((size_t)(b*40+o))<<HWSH)+off] = relu_(gg[o]*acc[j]+gb[o]);
    }
  }
}

// ---- offsets conv 3x3 SAME: 80ch -> 27ch, per edge ----
template<int STAGE>
__global__ __launch_bounds__(256) void k_off(
    const float* __restrict__ nodes, const float* __restrict__ h1,
    const float* __restrict__ wot, const float* __restrict__ bo,
    float* __restrict__ om)
{
  const int bid = blockIdx.x;
  const int e = bid >> 7;
  const int b = (bid >> 6) & 1;
  const int h = bid & 63;
  const int p = threadIdx.x & 63;
  const int wv = __builtin_amdgcn_readfirstlane(threadIdx.x >> 6);
  const int o0 = wv*7;
  const int no = (wv==3) ? 6 : 7;
  const int sn = c_src[e], dn = c_dst[e];
  float acc[7];
  #pragma unroll
  for (int j=0;j<7;j++) acc[j] = (j<no) ? bo[e*27+o0+j] : 0.f;
  #pragma unroll 2
  for (int c=0;c<80;c++){
    const float* cb;
    if (STAGE==1){
      int cc = (c<40) ? (sn*40+c) : (dn*40+c-40);
      cb = nodes + (((size_t)(b*240+cc))<<HWSH);
    } else {
      cb = h1 + (((size_t)((e*2+b)*80+c))<<HWSH);
    }
    const float* wc = wot + (size_t)((e*80+c)*9)*27 + o0;
    #pragma unroll
    for (int ky=0;ky<3;ky++){
      int hy = h+ky-1;
      if (hy < 0 || hy > 63) continue;
      float x0 = cb[(hy<<6) + p];
      float xm = __shfl_up(x0, 1);
      float xq = __shfl_down(x0, 1);
      xm = (p>0)  ? xm : 0.f;
      xq = (p<63) ? xq : 0.f;
      const float* wr = wc + ky*81;
      #pragma unroll
      for (int j=0;j<7;j++){
        acc[j] = fmaf(xm, wr[j],    acc[j]);
        acc[j] = fmaf(x0, wr[27+j], acc[j]);
        acc[j] = fmaf(xq, wr[54+j], acc[j]);
      }
    }
  }
  const int off = (h<<6)+p;
  for (int j=0;j<no;j++)
    om[(((size_t)((e*2+b)*27 + o0 + j))<<HWSH)+off] = acc[j];
}

// ======== k_dcn: bilinear gather (fp32) -> LDS bf16 hi/lo -> MFMA conv ====
// grid 1280 = e*128 + b*64 + h; block 256 = 4 waves.
// LDS A-tile: sA[px 0..63][c: 0..95 hi | 96..191 lo] ushort, CSTR=196.
// Per tap: gather 20ch/thread -> barrier -> 3 Ksteps x NT tiles x 2 MFMA -> barrier.
// A frag: m=lane&15 -> px = wv*16+(lane&15); k=(lane>>4)*8+j -> c.
// D: col n = nt*16+(lane&15), row -> px = wv*16+(lane>>4)*4+reg.
template<int STAGE>
__global__ __launch_bounds__(256) void k_dcn(
    const float* __restrict__ nodes, const float* __restrict__ h1,
    const float* __restrict__ om, const unsigned short* __restrict__ bs,
    const float* __restrict__ bng, const float* __restrict__ bnb,
    const float* __restrict__ attw, const float* __restrict__ attb,
    float* __restrict__ outp)
{
  constexpr int OUTC = (STAGE==1) ? 80 : 40;
  constexpr int NT   = (STAGE==1) ? 5 : 3;
  __shared__ unsigned short sA[64][196];    // 24.5 KB
  __shared__ float s_att[64];
  const int bid = blockIdx.x;
  const int e = bid >> 7;
  const int b = (bid >> 6) & 1;
  const int h = bid & 63;
  const int p = threadIdx.x & 63;
  const int wv = __builtin_amdgcn_readfirstlane(threadIdx.x >> 6);
  const int off = (h<<6) + p;
  const int sn = c_src[e], dn = c_dst[e];

  // preload 27 offset-map values (static indexing; tap loop fully unrolled)
  const float* ombase = om + (((size_t)((e*2+b)*27))<<HWSH) + off;
  float omv[27];
  #pragma unroll
  for (int i=0;i<27;i++) omv[i] = ombase[((size_t)i)<<HWSH];

  // gather base: this thread covers channels [wv*20, wv*20+20)
  const float* gbase;
  if (STAGE==1){
    gbase = (wv<2) ? nodes + (((size_t)(b*240 + sn*40 + wv*20))<<HWSH)
                   : nodes + (((size_t)(b*240 + dn*40 + (wv-2)*20))<<HWSH);
  } else {
    gbase = h1 + (((size_t)((e*2+b)*80 + wv*20))<<HWSH);
  }

  // zero-pad channels 80..95 (hi and lo planes), written once
  *(unsigned int*)&sA[p][80  + wv*4]     = 0u;
  *(unsigned int*)&sA[p][80  + wv*4 + 2] = 0u;
  *(unsigned int*)&sA[p][176 + wv*4]     = 0u;
  *(unsigned int*)&sA[p][176 + wv*4 + 2] = 0u;

  // stage2: wave 0 computes per-pixel attention factor (2 - sigmoid(att))
  if (STAGE==2 && wv==0){
    float at = attb[e];
    for (int c=0;c<40;c++)
      at = fmaf(nodes[(((size_t)(b*240+sn*40+c))<<HWSH)+off], attw[e*40+c], at);
    s_att[p] = 2.f - sigm_(at);
  }

  f32x4 acc[NT];
  #pragma unroll
  for (int nt=0;nt<NT;nt++)
    #pragma unroll
    for (int r=0;r<4;r++) acc[nt][r] = 0.f;

  const int lane = threadIdx.x & 63;
  const int l15 = lane & 15;
  const int lg  = lane >> 4;
  const int px_r = (wv<<4) + l15;

  #pragma unroll
  for (int k=0;k<9;k++){
    // ---- sampling context for tap k (register-only math) ----
    float dyv = omv[2*k], dxv = omv[2*k+1];
    float mv  = sigm_(omv[18+k]);
    float py = dyv + (float)(k/3 - 1 + h);
    float px = dxv + (float)(k%3 - 1) + (float)p;
    float y0f = floorf(py), x0f = floorf(px);
    float wy = py - y0f, wx = px - x0f;
    int y0 = (int)y0f, x0i = (int)x0f;
    int y1 = y0+1, x1i = x0i+1;
    bool yv0 = (y0>=0)&&(y0<64),  yv1 = (y1>=0)&&(y1<64);
    bool xv0 = (x0i>=0)&&(x0i<64), xv1 = (x1i>=0)&&(x1i<64);
    float w00 = (yv0&&xv0) ? (1.f-wy)*(1.f-wx)*mv : 0.f;
    float w01 = (yv0&&xv1) ? (1.f-wy)*wx*mv       : 0.f;
    float w10 = (yv1&&xv0) ? wy*(1.f-wx)*mv       : 0.f;
    float w11 = (yv1&&xv1) ? wy*wx*mv             : 0.f;
    int yc0 = min(max(y0 ,0),63), yc1 = min(max(y1 ,0),63);
    int xc0 = min(max(x0i,0),63), xc1 = min(max(x1i,0),63);
    int a00 = (yc0<<6)+xc0, a01 = (yc0<<6)+xc1;
    int a10 = (yc1<<6)+xc0, a11 = (yc1<<6)+xc1;

    // ---- gather 20 channels, convert hi/lo bf16, write LDS ----
    #pragma unroll
    for (int cj=0;cj<20;cj+=2){
      const float* cb0 = gbase + (((size_t)cj)<<HWSH);
      const float* cb1 = gbase + (((size_t)(cj+1))<<HWSH);
      float s0 = fmaf(w00,cb0[a00], fmaf(w01,cb0[a01], fmaf(w10,cb0[a10], w11*cb0[a11])));
      float s1 = fmaf(w00,cb1[a00], fmaf(w01,cb1[a01], fmaf(w10,cb1[a10], w11*cb1[a11])));
      unsigned short h0 = bf16rne(s0), h1_ = bf16rne(s1);
      unsigned short l0 = bf16rne(s0 - bf16f(h0)), l1 = bf16rne(s1 - bf16f(h1_));
      *(unsigned int*)&sA[p][wv*20 + cj]      = (unsigned int)h0 | ((unsigned int)h1_<<16);
      *(unsigned int*)&sA[p][96 + wv*20 + cj] = (unsigned int)l0 | ((unsigned int)l1<<16);
    }
    __syncthreads();

    // ---- MFMA: 3 Ksteps x NT tiles x (hi,lo) ----
    #pragma unroll
    for (int kst=0;kst<3;kst++){
      const int c0 = kst*32 + lg*8;
      union { unsigned int u[4]; short8 v; } ah, al;
      const unsigned int* ph = (const unsigned int*)&sA[px_r][c0];
      const unsigned int* pl = (const unsigned int*)&sA[px_r][96 + c0];
      ah.u[0]=ph[0]; ah.u[1]=ph[1]; ah.u[2]=ph[2]; ah.u[3]=ph[3];
      al.u[0]=pl[0]; al.u[1]=pl[1]; al.u[2]=pl[2]; al.u[3]=pl[3];
      #pragma unroll
      for (int nt=0;nt<NT;nt++){
        union { unsigned int u[4]; short8 v; } bf;
        const unsigned int* pb2 = (const unsigned int*)
          (bs + ((size_t)((((e*9+k)*3 + kst)*NT + nt)*64 + lane))*8);
        bf.u[0]=pb2[0]; bf.u[1]=pb2[1]; bf.u[2]=pb2[2]; bf.u[3]=pb2[3];
        acc[nt] = __builtin_amdgcn_mfma_f32_16x16x32_bf16(ah.v, bf.v, acc[nt], 0,0,0);
        acc[nt] = __builtin_amdgcn_mfma_f32_16x16x32_bf16(al.v, bf.v, acc[nt], 0,0,0);
      }
    }
    __syncthreads();
  }

  // ---- epilogue ----
  if (STAGE==1){
    #pragma unroll
    for (int nt=0;nt<NT;nt++){
      int n = nt*16 + l15;
      float g = bng[e*80+n], bb = bnb[e*80+n];
      #pragma unroll
      for (int r=0;r<4;r++){
        int pxs = (wv<<4) + lg*4 + r;
        outp[(((size_t)((e*2+b)*80+n))<<HWSH) + (h<<6) + pxs] = relu_(g*acc[nt][r] + bb);
      }
    }
  } else {
    #pragma unroll
    for (int nt=0;nt<NT;nt++){
      int n = nt*16 + l15;
      if (n < 40){
        float g = bng[e*40+n], bb = bnb[e*40+n];
        #pragma unroll
        for (int r=0;r<4;r++){
          int pxs = (wv<<4) + lg*4 + r;
          float fac = s_att[pxs];
          float v = relu_(g*acc[nt][r] + bb) * fac;
          atomicAdd(&outp[(((size_t)((dn*2+b)*40+n))<<HWSH) + (h<<6) + pxs], v);
        }
      }
    }
  }
}

// ---- node update: 2-layer 1x1 MLP -> new_bn [2,240,4096] ----
__global__ __launch_bounds__(128) void k_upd(
    const float* __restrict__ nodes, const float* __restrict__ msgs,
    const float* __restrict__ uw1t, const float* __restrict__ g1, const float* __restrict__ b1,
    const float* __restrict__ uw2t, const float* __restrict__ g2, const float* __restrict__ b2,
    float* __restrict__ newbn)
{
  const int bid = blockIdx.x;
  const int n = bid >> 6;
  const int r = bid & 63;
  const int b = r >> 5;
  const int pix = ((r & 31) << 7) + threadIdx.x;
  float a1[32];
  #pragma unroll
  for (int j=0;j<32;j++) a1[j]=0.f;
  for (int c=0;c<40;c++){
    float xv = nodes[(((size_t)(b*240+n*40+c))<<HWSH)+pix];
    const float* wr = uw1t + (n*80+c)*32;
    #pragma unroll
    for (int j=0;j<32;j++) a1[j]=fmaf(xv,wr[j],a1[j]);
  }
  for (int c=0;c<40;c++){
    float xv = msgs[(((size_t)((n*2+b)*40+c))<<HWSH)+pix];
    const float* wr = uw1t + (n*80+40+c)*32;
    #pragma unroll
    for (int j=0;j<32;j++) a1[j]=fmaf(xv,wr[j],a1[j]);
  }
  #pragma unroll
  for (int j=0;j<32;j++) a1[j] = relu_(g1[n*32+j]*a1[j]+b1[n*32+j]);
  float a2[40];
  #pragma unroll
  for (int j=0;j<40;j++) a2[j]=0.f;
  for (int c=0;c<32;c++){
    const float* wr = uw2t + (n*32+c)*40;
    #pragma unroll
    for (int j=0;j<40;j++) a2[j]=fmaf(a1[c],wr[j],a2[j]);
  }
  #pragma unroll
  for (int j=0;j<40;j++)
    newbn[(((size_t)(b*240+n*40+j))<<HWSH)+pix] = relu_(g2[n*40+j]*a2[j]+b2[n*40+j]);
}

// ======== k_post: xp_infer concat (4288 blocks) + pg classifier (224) ====
__global__ __launch_bounds__(256) void k_post(
    const float* __restrict__ xp, const float* __restrict__ bg,
    const float* __restrict__ newbn, const float* __restrict__ nodes,
    const float* __restrict__ cw, const float* __restrict__ cb,
    const float* __restrict__ cnw, const float* __restrict__ cnb,
    float* __restrict__ out)
{
  if (blockIdx.x < 4288){
    int i4 = blockIdx.x*256+threadIdx.x;   // exactly 1097728
    int idx = i4 << 2;
    int b = idx / (536*4096);
    int r = idx - b*(536*4096);
    int ch = r >> HWSH;
    int off = r & 4095;
    float4 v;
    if (ch < 256)      v = *(const float4*)&xp[(((size_t)(b*256+ch))<<HWSH)+off];
    else if (ch < 296) v = *(const float4*)&bg[(((size_t)(b*40+ch-256))<<HWSH)+off];
    else               v = *(const float4*)&newbn[(((size_t)(b*240+ch-296))<<HWSH)+off];
    *(float4*)&out[idx] = v;
  } else {
    int idx = (blockIdx.x-4288)*256+threadIdx.x;   // exactly 57344
    int b = idx / (7*4096);
    int r = idx - b*7*4096;
    int g = r >> HWSH;
    int off = r & 4095;
    float a = cb[g] + cnb[g];
    if (g == 0){
      for (int c=0;c<40;c++){
        float v = bg[(((size_t)(b*40+c))<<HWSH)+off];
        a = fmaf(v, cw[c]+cnw[c], a);
      }
    } else {
      for (int c=0;c<40;c++){
        float vo = nodes[(((size_t)(b*240+(g-1)*40+c))<<HWSH)+off];
        float vn = newbn[(((size_t)(b*240+(g-1)*40+c))<<HWSH)+off];
        a = fmaf(vo, cw[g*40+c], a);
        a = fmaf(vn, cnw[g*40+c], a);
      }
    }
    out[4390912 + idx] = a;
  }
}

extern "C" void kernel_launch(void* const* d_in, const int* in_sizes, int n_in,
                              void* d_out, int out_size, void* d_ws, size_t ws_size,
                              hipStream_t stream)
{
  const float* xp       = (const float*)d_in[0];
  const float* xh       = (const float*)d_in[1];
  const float* xf       = (const float*)d_in[2];
  const float* p_w      = (const float*)d_in[3];
  const float* p_g      = (const float*)d_in[4];
  const float* p_b      = (const float*)d_in[5];
  const float* bg_w     = (const float*)d_in[6];
  const float* bg_g     = (const float*)d_in[7];
  const float* bg_b     = (const float*)d_in[8];
  const float* e_off1_w = (const float*)d_in[9];
  const float* e_off1_b = (const float*)d_in[10];
  const float* e_dcn1_w = (const float*)d_in[11];
  const float* e_bn1_g  = (const float*)d_in[12];
  const float* e_bn1_b  = (const float*)d_in[13];
  const float* e_off2_w = (const float*)d_in[14];
  const float* e_off2_b = (const float*)d_in[15];
  const float* e_dcn2_w = (const float*)d_in[16];
  const float* e_bn2_g  = (const float*)d_in[17];
  const float* e_bn2_b  = (const float*)d_in[18];
  const float* e_att_w  = (const float*)d_in[19];
  const float* e_att_b  = (const float*)d_in[20];
  const float* u_w1     = (const float*)d_in[21];
  const float* u_g1     = (const float*)d_in[22];
  const float* u_b1     = (const float*)d_in[23];
  const float* u_w2     = (const float*)d_in[24];
  const float* u_g2     = (const float*)d_in[25];
  const float* u_b2     = (const float*)d_in[26];
  const float* cls_w    = (const float*)d_in[27];
  const float* cls_b    = (const float*)d_in[28];
  const float* cls_nw   = (const float*)d_in[29];
  const float* cls_nb   = (const float*)d_in[30];

  float* ws    = (float*)d_ws;
  float* nodes = ws + NODES_OFF;
  float* bgb   = ws + BG_OFF;
  float* h1    = ws + H1_OFF;
  float* om    = ws + OM_OFF;
  float* msgs  = ws + MSGS_OFF;
  float* newbn = ws + NEWBN_OFF;
  float* wo1t  = ws + WO1T_OFF;
  float* wo2t  = ws + WO2T_OFF;
  float* pwt   = ws + PWT_OFF;
  float* bgwt  = ws + BGWT_OFF;
  float* uw1t  = ws + UW1T_OFF;
  float* uw2t  = ws + UW2T_OFF;
  const unsigned short* bs1u = (const unsigned short*)(ws + BS1_OFF);
  const unsigned short* bs2u = (const unsigned short*)(ws + BS2_OFF);

  k_pre<<<10190, 256, 0, stream>>>(e_off1_w, e_off2_w, p_w, bg_w, u_w1, u_w2,
                                   e_dcn1_w, e_dcn2_w, ws);
  k_gemm1<<<1024, 256, 0, stream>>>(xp, xh, xf, pwt, p_g, p_b, bgwt, bg_g, bg_b,
                                    nodes, bgb);
  k_off<1><<<1280, 256, 0, stream>>>(nodes, nullptr, wo1t, e_off1_b, om);
  k_dcn<1><<<1280, 256, 0, stream>>>(nodes, nullptr, om, bs1u, e_bn1_g, e_bn1_b,
                                     nullptr, nullptr, h1);
  k_off<2><<<1280, 256, 0, stream>>>(nullptr, h1, wo2t, e_off2_b, om);
  k_dcn<2><<<1280, 256, 0, stream>>>(nodes, h1, om, bs2u, e_bn2_g, e_bn2_b,
                                     e_att_w, e_att_b, msgs);
  k_upd<<<384, 128, 0, stream>>>(nodes, msgs, uw1t, u_g1, u_b1, uw2t, u_g2, u_b2, newbn);
  k_post<<<4512, 256, 0, stream>>>(xp, bgb, newbn, nodes, cls_w, cls_b, cls_nw, cls_nb,
                                   (float*)d_out);
}